// Round 2
// baseline (226.295 us; speedup 1.0000x reference)
//
#include <hip/hip_runtime.h>

#define Cc 8
#define Hh 128
#define Ww 128
#define Nn 64
#define Bb 8
#define Dd 169            // (C+2)*C + C + C*C + C + C + 1
#define HW (Hh * Ww)
#define SPLIT 4           // blocks per (b,n)
#define PXB (HW / SPLIT)  // pixels per block = 4096
#define ITERS (PXB / (256 * 4))  // 4 iterations of 4 pixels per thread

#define INV128 (1.0f / 128.0f)

__global__ __launch_bounds__(256, 4)
void seg_dice_main(const float* __restrict__ seg_feat,
                   const float* __restrict__ conv_weight,
                   const float* __restrict__ mask,
                   const int*   __restrict__ ind,
                   const float* __restrict__ target,
                   float* __restrict__ ws) {
    const int blk   = blockIdx.x;
    const int bn    = blk >> 2;          // / SPLIT
    const int chunk = blk & (SPLIT - 1);
    const int b     = bn >> 6;
    const int tid   = threadIdx.x;

    __shared__ float w_s[Dd];
    const int ind_bn = ind[bn];

    // gather weight vector: conv_weight[b, d, ind]
    for (int i = tid; i < Dd; i += 256)
        w_s[i] = conv_weight[(size_t)b * Dd * HW + (size_t)i * HW + ind_bn];
    __syncthreads();

    const float m  = mask[bn];
    const float x0 = (float)(ind_bn & (Ww - 1));
    const float y0 = (float)(ind_bn >> 7);

    const float* seg_b  = seg_feat + (size_t)b * Cc * HW;
    const float* tgt_bn = target   + (size_t)bn * HW;

    float inter = 0.f, psum = 0.f, tsum = 0.f;

    const int pbase = chunk * PXB + (tid << 2);

    #pragma unroll 1
    for (int it = 0; it < ITERS; ++it) {
        const int p = pbase + it * 1024;

        const float4 t4 = *(const float4*)(tgt_bn + p);
        float4 f[8];
        #pragma unroll
        for (int c = 0; c < 8; ++c) f[c] = *(const float4*)(seg_b + c * HW + p);

        const float yr = ((float)(p >> 7)        - y0) * INV128;
        const float xb = ((float)(p & (Ww - 1)) - x0) * INV128;

        // ---- layer 1: 10 -> 8, relu.  yr+bias folded per row; xr varies per px
        float h10[8], h11[8], h12[8], h13[8];
        #pragma unroll
        for (int o = 0; o < 8; ++o) {
            const float w8 = w_s[o * 10 + 8];
            const float w9 = w_s[o * 10 + 9];
            const float base_o = fmaf(w9, yr, w_s[80 + o]);
            float a0 = fmaf(w8, xb,               base_o);
            float a1 = fmaf(w8, xb +     INV128,  base_o);
            float a2 = fmaf(w8, xb + 2.f*INV128,  base_o);
            float a3 = fmaf(w8, xb + 3.f*INV128,  base_o);
            #pragma unroll
            for (int c = 0; c < 8; ++c) {
                const float wv = w_s[o * 10 + c];
                a0 = fmaf(wv, f[c].x, a0);
                a1 = fmaf(wv, f[c].y, a1);
                a2 = fmaf(wv, f[c].z, a2);
                a3 = fmaf(wv, f[c].w, a3);
            }
            h10[o] = fmaxf(a0, 0.f); h11[o] = fmaxf(a1, 0.f);
            h12[o] = fmaxf(a2, 0.f); h13[o] = fmaxf(a3, 0.f);
        }

        // ---- layer 2: 8 -> 8, relu
        float h20[8], h21[8], h22[8], h23[8];
        #pragma unroll
        for (int o = 0; o < 8; ++o) {
            const float bo = w_s[152 + o];
            float a0 = bo, a1 = bo, a2 = bo, a3 = bo;
            #pragma unroll
            for (int c = 0; c < 8; ++c) {
                const float wv = w_s[88 + o * 8 + c];
                a0 = fmaf(wv, h10[c], a0);
                a1 = fmaf(wv, h11[c], a1);
                a2 = fmaf(wv, h12[c], a2);
                a3 = fmaf(wv, h13[c], a3);
            }
            h20[o] = fmaxf(a0, 0.f); h21[o] = fmaxf(a1, 0.f);
            h22[o] = fmaxf(a2, 0.f); h23[o] = fmaxf(a3, 0.f);
        }

        // ---- layer 3: 8 -> 1, sigmoid
        const float b3r = w_s[168];
        float z0 = b3r, z1 = b3r, z2 = b3r, z3 = b3r;
        #pragma unroll
        for (int c = 0; c < 8; ++c) {
            const float wv = w_s[160 + c];
            z0 = fmaf(wv, h20[c], z0);
            z1 = fmaf(wv, h21[c], z1);
            z2 = fmaf(wv, h22[c], z2);
            z3 = fmaf(wv, h23[c], z3);
        }
        const float e0 = __expf(-z0), e1 = __expf(-z1);
        const float e2 = __expf(-z2), e3 = __expf(-z3);
        const float o0 = __builtin_amdgcn_rcpf(1.f + e0);
        const float o1 = __builtin_amdgcn_rcpf(1.f + e1);
        const float o2 = __builtin_amdgcn_rcpf(1.f + e2);
        const float o3 = __builtin_amdgcn_rcpf(1.f + e3);

        // ---- dice partials (mask factored out: scale by m*m at the end)
        inter = fmaf(o0, t4.x, inter);
        inter = fmaf(o1, t4.y, inter);
        inter = fmaf(o2, t4.z, inter);
        inter = fmaf(o3, t4.w, inter);
        psum  = fmaf(o0, o0, psum);
        psum  = fmaf(o1, o1, psum);
        psum  = fmaf(o2, o2, psum);
        psum  = fmaf(o3, o3, psum);
        tsum  = fmaf(t4.x, t4.x, tsum);
        tsum  = fmaf(t4.y, t4.y, tsum);
        tsum  = fmaf(t4.z, t4.z, tsum);
        tsum  = fmaf(t4.w, t4.w, tsum);
    }

    const float m2 = m * m;
    inter *= m2; psum *= m2; tsum *= m2;

    // wave reduce (64-lane) then cross-wave via LDS
    #pragma unroll
    for (int off = 32; off > 0; off >>= 1) {
        inter += __shfl_down(inter, off);
        psum  += __shfl_down(psum,  off);
        tsum  += __shfl_down(tsum,  off);
    }
    __shared__ float red[3][4];
    const int wave = tid >> 6;
    if ((tid & 63) == 0) { red[0][wave] = inter; red[1][wave] = psum; red[2][wave] = tsum; }
    __syncthreads();
    if (tid == 0) {
        const float i2 = red[0][0] + red[0][1] + red[0][2] + red[0][3];
        const float p2 = red[1][0] + red[1][1] + red[1][2] + red[1][3];
        const float t2 = red[2][0] + red[2][1] + red[2][2] + red[2][3];
        atomicAdd(&ws[b * 3 + 0], i2);
        atomicAdd(&ws[b * 3 + 1], p2);
        atomicAdd(&ws[b * 3 + 2], t2);
    }
}

__global__ void seg_dice_final(const float* __restrict__ ws, float* __restrict__ out) {
    if (threadIdx.x == 0) {
        float acc = 0.f;
        #pragma unroll
        for (int b = 0; b < Bb; ++b) {
            const float inter = ws[b * 3 + 0];
            const float p     = ws[b * 3 + 1];
            const float t     = ws[b * 3 + 2];
            acc += 1.0f - (2.0f * inter + 1.0f) / (p + t + 1.0f);
        }
        out[0] = acc * (1.0f / (float)Bb);
    }
}

extern "C" void kernel_launch(void* const* d_in, const int* in_sizes, int n_in,
                              void* d_out, int out_size, void* d_ws, size_t ws_size,
                              hipStream_t stream) {
    const float* seg_feat    = (const float*)d_in[0];
    const float* conv_weight = (const float*)d_in[1];
    const float* mask        = (const float*)d_in[2];
    const int*   ind         = (const int*)d_in[3];
    const float* target      = (const float*)d_in[4];
    float* out = (float*)d_out;
    float* ws  = (float*)d_ws;

    hipMemsetAsync(ws, 0, Bb * 3 * sizeof(float), stream);

    seg_dice_main<<<Bb * Nn * SPLIT, 256, 0, stream>>>(seg_feat, conv_weight, mask, ind, target, ws);
    seg_dice_final<<<1, 64, 0, stream>>>(ws, out);
}

// Round 3
// 46.632 us; speedup vs baseline: 4.8528x; 4.8528x over previous
//
#include <hip/hip_runtime.h>

#define Cc 8
#define Hh 128
#define Ww 128
#define Nn 64
#define Bb 8
#define Dd 169            // (C+2)*C + C + C*C + C + C + 1
#define HW (Hh * Ww)
#define SPLIT 4           // blocks per (b,n)
#define PXB (HW / SPLIT)  // 4096 pixels per block
#define ITERS (PXB / (256 * 4))  // 4 iterations of 4 px per thread

#define INV128 (1.0f / 128.0f)

__device__ __forceinline__ float pick(float4 v, int j) {
    return j == 0 ? v.x : j == 1 ? v.y : j == 2 ? v.z : v.w;
}

__global__ __launch_bounds__(256)
__attribute__((amdgpu_waves_per_eu(2, 2)))   // register budget 256: keep all 169 weights resident
void seg_dice_main(const float* __restrict__ seg_feat,
                   const float* __restrict__ conv_weight,
                   const float* __restrict__ mask,
                   const int*   __restrict__ ind,
                   const float* __restrict__ target,
                   float* __restrict__ ws) {
    const int blk   = blockIdx.x;
    const int bn    = blk >> 2;          // / SPLIT
    const int chunk = blk & (SPLIT - 1);
    const int b     = bn >> 6;
    const int tid   = threadIdx.x;

    __shared__ float w_s[Dd];
    const int ind_bn = ind[bn];

    // gather weight vector: conv_weight[b, d, ind]
    for (int i = tid; i < Dd; i += 256)
        w_s[i] = conv_weight[(size_t)b * Dd * HW + (size_t)i * HW + ind_bn];
    __syncthreads();

    // ---- ALL weights to registers; no LDS reads in the pixel loop ----
    float W1[8][10], B1[8], W2[8][8], B2[8], W3[8];
    #pragma unroll
    for (int o = 0; o < 8; ++o) {
        #pragma unroll
        for (int i = 0; i < 10; ++i) W1[o][i] = w_s[o * 10 + i];
        B1[o] = w_s[80 + o];
        #pragma unroll
        for (int i = 0; i < 8; ++i)  W2[o][i] = w_s[88 + o * 8 + i];
        B2[o] = w_s[152 + o];
        W3[o] = w_s[160 + o];
    }
    const float B3 = w_s[168];

    const float m  = mask[bn];
    const float x0 = (float)(ind_bn & (Ww - 1));
    const float y0 = (float)(ind_bn >> 7);

    const float* seg_b  = seg_feat + (size_t)b * Cc * HW;
    const float* tgt_bn = target   + (size_t)bn * HW;

    float inter = 0.f, ps = 0.f, ts = 0.f;
    const int pbase = chunk * PXB + (tid << 2);

    #pragma unroll 1
    for (int it = 0; it < ITERS; ++it) {
        const int p = pbase + it * 1024;

        const float4 t4 = *(const float4*)(tgt_bn + p);
        float4 f4[8];
        #pragma unroll
        for (int c = 0; c < 8; ++c) f4[c] = *(const float4*)(seg_b + c * HW + p);

        const float yr = ((float)(p >> 7)        - y0) * INV128;
        const float xb = ((float)(p & (Ww - 1)) - x0) * INV128;

        #pragma unroll
        for (int j = 0; j < 4; ++j) {
            const float xr = xb + (float)j * INV128;

            float h1[8];
            #pragma unroll
            for (int o = 0; o < 8; ++o) {
                float a = fmaf(W1[o][9], yr, B1[o]);
                a = fmaf(W1[o][8], xr, a);
                #pragma unroll
                for (int c = 0; c < 8; ++c) a = fmaf(W1[o][c], pick(f4[c], j), a);
                h1[o] = fmaxf(a, 0.f);
            }
            float h2[8];
            #pragma unroll
            for (int o = 0; o < 8; ++o) {
                float a = B2[o];
                #pragma unroll
                for (int c = 0; c < 8; ++c) a = fmaf(W2[o][c], h1[c], a);
                h2[o] = fmaxf(a, 0.f);
            }
            float z = B3;
            #pragma unroll
            for (int c = 0; c < 8; ++c) z = fmaf(W3[c], h2[c], z);

            const float o_ = __builtin_amdgcn_rcpf(1.f + __expf(-z));
            const float tv = pick(t4, j);
            inter = fmaf(o_, tv, inter);
            ps    = fmaf(o_, o_, ps);
            ts    = fmaf(tv, tv, ts);
        }
    }

    const float m2 = m * m;
    inter *= m2; ps *= m2; ts *= m2;

    // wave reduce then cross-wave via LDS
    #pragma unroll
    for (int off = 32; off > 0; off >>= 1) {
        inter += __shfl_down(inter, off);
        ps    += __shfl_down(ps,    off);
        ts    += __shfl_down(ts,    off);
    }
    __shared__ float red[3][4];
    const int wave = tid >> 6;
    if ((tid & 63) == 0) { red[0][wave] = inter; red[1][wave] = ps; red[2][wave] = ts; }
    __syncthreads();
    if (tid == 0) {
        const int lb = (bn & 63) * SPLIT + chunk;   // 0..255 within batch b
        ws[(b * 3 + 0) * 256 + lb] = red[0][0] + red[0][1] + red[0][2] + red[0][3];
        ws[(b * 3 + 1) * 256 + lb] = red[1][0] + red[1][1] + red[1][2] + red[1][3];
        ws[(b * 3 + 2) * 256 + lb] = red[2][0] + red[2][1] + red[2][2] + red[2][3];
    }
}

// deterministic epilogue: 24 series (8 b x 3 comps) x 256 partials
__global__ void seg_dice_final(const float* __restrict__ ws, float* __restrict__ out) {
    __shared__ float red[24][4];
    const int tid = threadIdx.x;  // 128 threads
    if (tid < 96) {
        const int series = tid >> 2;   // 0..23
        const int part   = tid & 3;    // 0..3
        const float4* p = (const float4*)(ws + series * 256 + part * 64);
        float s = 0.f;
        #pragma unroll
        for (int i = 0; i < 16; ++i) { const float4 v = p[i]; s += (v.x + v.y) + (v.z + v.w); }
        red[series][part] = s;
    }
    __syncthreads();
    if (tid == 0) {
        float acc = 0.f;
        #pragma unroll
        for (int b = 0; b < Bb; ++b) {
            const float inter = red[b*3+0][0] + red[b*3+0][1] + red[b*3+0][2] + red[b*3+0][3];
            const float p2    = red[b*3+1][0] + red[b*3+1][1] + red[b*3+1][2] + red[b*3+1][3];
            const float t2    = red[b*3+2][0] + red[b*3+2][1] + red[b*3+2][2] + red[b*3+2][3];
            acc += 1.0f - (2.0f * inter + 1.0f) / (p2 + t2 + 1.0f);
        }
        out[0] = acc * (1.0f / (float)Bb);
    }
}

extern "C" void kernel_launch(void* const* d_in, const int* in_sizes, int n_in,
                              void* d_out, int out_size, void* d_ws, size_t ws_size,
                              hipStream_t stream) {
    const float* seg_feat    = (const float*)d_in[0];
    const float* conv_weight = (const float*)d_in[1];
    const float* mask        = (const float*)d_in[2];
    const int*   ind         = (const int*)d_in[3];
    const float* target      = (const float*)d_in[4];
    float* out = (float*)d_out;
    float* ws  = (float*)d_ws;

    seg_dice_main<<<Bb * Nn * SPLIT, 256, 0, stream>>>(seg_feat, conv_weight, mask, ind, target, ws);
    seg_dice_final<<<1, 128, 0, stream>>>(ws, out);
}